// Round 1
// baseline (14996.817 us; speedup 1.0000x reference)
//
#include <hip/hip_runtime.h>
#include <hip/hip_bf16.h>

using bf16 = __hip_bfloat16;

static constexpr int B_ = 4;
static constexpr int N_ = 4096;
static constexpr int H_ = 4;

// 8-term dot: a[8] (registers, from LDS) * w[0..7] (global, two float4 loads)
__device__ __forceinline__ float dot8(const float a[8], const float* __restrict__ w) {
  const float4* w4 = (const float4*)w;
  float4 x = w4[0];
  float4 y = w4[1];
  return a[0] * x.x + a[1] * x.y + a[2] * x.z + a[3] * x.w +
         a[4] * y.x + a[5] * y.y + a[6] * y.z + a[7] * y.w;
}

// ---------------- Q projection: Q[b,h,n,d] = sum_c emb[b,n,h*C4+c] * wq[h,d,c]
// grid (N/32, B*H, 2 modalities), block 256
template <int C4>
__global__ __launch_bounds__(256) void k_proj_q(const float* __restrict__ e0,
                                                const float* __restrict__ w0,
                                                bf16* __restrict__ o0,
                                                const float* __restrict__ e1,
                                                const float* __restrict__ w1,
                                                bf16* __restrict__ o1) {
  constexpr int J = C4 / 8;
  const float* emb = blockIdx.z ? e1 : e0;
  const float* wq = blockIdx.z ? w1 : w0;
  bf16* qout = blockIdx.z ? o1 : o0;
  const int bh = blockIdx.y, b = bh / H_, h = bh % H_;
  const int n0 = blockIdx.x * 32;
  const int tid = threadIdx.x;
  __shared__ float sE[32][C4 + 1];
  for (int idx = tid; idx < 32 * C4; idx += 256) {
    int r = idx / C4, c = idx % C4;
    sE[r][c] = emb[(size_t)(b * N_ + n0 + r) * (H_ * C4) + h * C4 + c];
  }
  __syncthreads();
  const int r = tid >> 3, dg = tid & 7;
  const float* wb = wq + h * C4 * C4;
  float acc[J];
#pragma unroll
  for (int j = 0; j < J; j++) acc[j] = 0.f;
  for (int cb = 0; cb < C4; cb += 8) {
    float a[8];
#pragma unroll
    for (int t = 0; t < 8; t++) a[t] = sE[r][cb + t];
#pragma unroll
    for (int j = 0; j < J; j++) acc[j] += dot8(a, wb + (dg + 8 * j) * C4 + cb);
  }
  const size_t ob = ((size_t)bh * N_ + n0 + r) * C4;
#pragma unroll
  for (int j = 0; j < J; j++) qout[ob + dg + 8 * j] = __float2bfloat16(acc[j]);
}

// ---------------- K/V projection with kvsplit gather
// grid (N/32, B*H, 4: K,V,Kd,Vd), block 256
__global__ __launch_bounds__(256) void k_proj_kv(
    const float* __restrict__ srcA, const float* __restrict__ srcB,
    const float* __restrict__ wk, const float* __restrict__ wv,
    const float* __restrict__ wkd, const float* __restrict__ wvd,
    bf16* __restrict__ oK, bf16* __restrict__ oV,
    bf16* __restrict__ oKd, bf16* __restrict__ oVd) {
  const int t = blockIdx.z;
  const float* src = (t < 2) ? srcA : srcB;
  const float* w = (t == 0) ? wk : (t == 1) ? wv : (t == 2) ? wkd : wvd;
  bf16* out = (t == 0) ? oK : (t == 1) ? oV : (t == 2) ? oKd : oVd;
  const int bh = blockIdx.y, b = bh / H_, h = bh % H_;
  const int n0 = blockIdx.x * 32;
  const int tid = threadIdx.x;
  __shared__ float sA[32][241];
  for (int idx = tid; idx < 32 * 240; idx += 256) {
    int r = idx / 240, c = idx % 240;
    int g;
    if (c < 16)       g = h * 16 + c;
    else if (c < 48)  g = 64 + h * 32 + (c - 16);
    else if (c < 112) g = 192 + h * 64 + (c - 48);
    else              g = 448 + h * 128 + (c - 112);
    sA[r][c] = src[(size_t)(b * N_ + n0 + r) * 960 + g];
  }
  __syncthreads();
  const int r = tid >> 3, dg = tid & 7;
  float acc[30];
#pragma unroll
  for (int j = 0; j < 30; j++) acc[j] = 0.f;
  for (int cb = 0; cb < 240; cb += 8) {
    float a[8];
#pragma unroll
    for (int t2 = 0; t2 < 8; t2++) a[t2] = sA[r][cb + t2];
#pragma unroll
    for (int j = 0; j < 30; j++) acc[j] += dot8(a, w + (dg + 8 * j) * 240 + cb);
  }
  const size_t ob = ((size_t)bh * N_ + n0 + r) * 240;
#pragma unroll
  for (int j = 0; j < 30; j++) out[ob + dg + 8 * j] = __float2bfloat16(acc[j]);
}

// ---------------- scores: sc[c,k] = (1/sqrt(960)) sum_n Q[n,c] * K[n,k]
// grid (C4/16, B*H, 2 modalities), block 256 (240 active compute lanes)
template <int C4>
__global__ __launch_bounds__(256) void k_scores(const bf16* __restrict__ q0,
                                                const bf16* __restrict__ k0_,
                                                float* __restrict__ s0,
                                                const bf16* __restrict__ q1,
                                                const bf16* __restrict__ k1_,
                                                float* __restrict__ s1) {
  const bf16* q = blockIdx.z ? q1 : q0;
  const bf16* kv = blockIdx.z ? k1_ : k0_;
  float* sc = blockIdx.z ? s1 : s0;
  const int bh = blockIdx.y;
  const int c0 = blockIdx.x * 16;
  const int tid = threadIdx.x;
  __shared__ __align__(16) float sQ[32][16];
  __shared__ float sK[32][241];
  const int cg = tid / 60, kg = tid - 60 * cg;  // cg 0..3 valid when tid<240
  const bool act = tid < 240;
  float acc[4][4];
#pragma unroll
  for (int i = 0; i < 4; i++)
#pragma unroll
    for (int j = 0; j < 4; j++) acc[i][j] = 0.f;
  for (int n0 = 0; n0 < N_; n0 += 32) {
    for (int idx = tid; idx < 32 * 16; idx += 256) {
      int rr = idx >> 4, cc = idx & 15;
      sQ[rr][cc] = __bfloat162float(q[((size_t)bh * N_ + n0 + rr) * C4 + c0 + cc]);
    }
    for (int idx = tid; idx < 32 * 240; idx += 256) {
      int rr = idx / 240, kk = idx % 240;
      sK[rr][kk] = __bfloat162float(kv[((size_t)bh * N_ + n0 + rr) * 240 + kk]);
    }
    __syncthreads();
    if (act) {
      for (int nn = 0; nn < 32; nn++) {
        const float4 qv = *(const float4*)&sQ[nn][cg * 4];
        const float qa[4] = {qv.x, qv.y, qv.z, qv.w};
        float ka[4];
#pragma unroll
        for (int j = 0; j < 4; j++) ka[j] = sK[nn][kg + 60 * j];
#pragma unroll
        for (int i = 0; i < 4; i++)
#pragma unroll
          for (int j = 0; j < 4; j++) acc[i][j] += qa[i] * ka[j];
      }
    }
    __syncthreads();
  }
  if (act) {
    const float rs = 0.0322748612183951f;  // 1/sqrt(960)
#pragma unroll
    for (int i = 0; i < 4; i++)
#pragma unroll
      for (int j = 0; j < 4; j++)
        sc[((size_t)bh * C4 + c0 + cg * 4 + i) * 240 + kg + 60 * j] = acc[i][j] * rs;
  }
}

// ---------------- InstanceNorm over (c,k) per (b,h), then softmax over k (240)
// grid (B*H, 1, 2 modalities), block 256 (4 waves)
__global__ __launch_bounds__(256) void k_inorm_softmax(float* __restrict__ p0,
                                                       float* __restrict__ p1,
                                                       int c4) {
  float* p = (blockIdx.z ? p1 : p0) + (size_t)blockIdx.x * c4 * 240;
  const int tid = threadIdx.x;
  const int tot = c4 * 240;
  float s = 0.f, s2 = 0.f;
  for (int idx = tid; idx < tot; idx += 256) {
    float v = p[idx];
    s += v;
    s2 += v * v;
  }
#pragma unroll
  for (int off = 32; off > 0; off >>= 1) {
    s += __shfl_xor(s, off);
    s2 += __shfl_xor(s2, off);
  }
  __shared__ float rsum[4], rsum2[4], smv[2];
  const int wid = tid >> 6, lane = tid & 63;
  if (lane == 0) { rsum[wid] = s; rsum2[wid] = s2; }
  __syncthreads();
  if (tid == 0) {
    float ts = rsum[0] + rsum[1] + rsum[2] + rsum[3];
    float ts2 = rsum2[0] + rsum2[1] + rsum2[2] + rsum2[3];
    float mean = ts / tot;
    float var = ts2 / tot - mean * mean;
    smv[0] = mean;
    smv[1] = rsqrtf(var + 1e-5f);
  }
  __syncthreads();
  const float mean = smv[0], rstd = smv[1];
  for (int c = wid; c < c4; c += 4) {  // one wave per row
    float* row = p + (size_t)c * 240;
    float x[4];
    float mx = -1e30f;
#pragma unroll
    for (int t = 0; t < 4; t++) {
      int k = lane + 64 * t;
      x[t] = (k < 240) ? (row[k] - mean) * rstd : -1e30f;
      mx = fmaxf(mx, x[t]);
    }
#pragma unroll
    for (int off = 32; off > 0; off >>= 1) mx = fmaxf(mx, __shfl_xor(mx, off));
    float e[4], sum = 0.f;
#pragma unroll
    for (int t = 0; t < 4; t++) {
      int k = lane + 64 * t;
      e[t] = (k < 240) ? expf(x[t] - mx) : 0.f;
      sum += e[t];
    }
#pragma unroll
    for (int off = 32; off > 0; off >>= 1) sum += __shfl_xor(sum, off);
    const float inv = 1.f / sum;
#pragma unroll
    for (int t = 0; t < 4; t++) {
      int k = lane + 64 * t;
      if (k < 240) row[k] = e[t] * inv;
    }
  }
}

// ---------------- PV: ctx[b,n,choff+h*C4+c] = sum_k probs[c,k] * V[b,h,n,k]
// grid (N/32, B*H, 2 modalities), block 256
template <int C4>
__global__ __launch_bounds__(256) void k_pv(const float* __restrict__ p0,
                                            const bf16* __restrict__ v0,
                                            bf16* __restrict__ c0_,
                                            const float* __restrict__ p1,
                                            const bf16* __restrict__ v1,
                                            bf16* __restrict__ c1_,
                                            int choff) {
  constexpr int J = C4 / 8;
  const float* probs = blockIdx.z ? p1 : p0;
  const bf16* v = blockIdx.z ? v1 : v0;
  bf16* ctx = blockIdx.z ? c1_ : c0_;
  const int bh = blockIdx.y, b = bh / H_, h = bh % H_;
  const int n0 = blockIdx.x * 32;
  const int tid = threadIdx.x;
  __shared__ float sV[32][241];
  for (int idx = tid; idx < 32 * 240; idx += 256) {
    int r = idx / 240, k = idx % 240;
    sV[r][k] = __bfloat162float(v[((size_t)bh * N_ + n0 + r) * 240 + k]);
  }
  __syncthreads();
  const int r = tid >> 3, cg = tid & 7;
  float acc[J];
#pragma unroll
  for (int j = 0; j < J; j++) acc[j] = 0.f;
  const float* pb = probs + (size_t)bh * C4 * 240;
  for (int kb = 0; kb < 240; kb += 8) {
    float a[8];
#pragma unroll
    for (int t = 0; t < 8; t++) a[t] = sV[r][kb + t];
#pragma unroll
    for (int j = 0; j < J; j++) acc[j] += dot8(a, pb + (size_t)(cg + 8 * j) * 240 + kb);
  }
  const size_t ob = (size_t)(b * N_ + n0 + r) * 960 + choff + h * C4;
#pragma unroll
  for (int j = 0; j < J; j++) ctx[ob + cg + 8 * j] = __float2bfloat16(acc[j]);
}

// ---------------- out[b,n,obase+d] = sum_c ctx[b,n,choff+c] * w[d,c]
// grid (N/32, B, 2 * CS/64), block 256
template <int CS>
__global__ __launch_bounds__(256) void k_wout(const bf16* __restrict__ c0_,
                                              const float* __restrict__ w0,
                                              int ob0,
                                              const bf16* __restrict__ c1_,
                                              const float* __restrict__ w1,
                                              int ob1,
                                              float* __restrict__ out, int choff) {
  constexpr int CST = (CS < 256) ? CS : 256;
  constexpr int DB = CS / 64;
  const int m = blockIdx.z / DB;
  const int d0 = (blockIdx.z % DB) * 64;
  const bf16* ctx = m ? c1_ : c0_;
  const float* w = m ? w1 : w0;
  const int obase = m ? ob1 : ob0;
  const int b = blockIdx.y;
  const int n0 = blockIdx.x * 32;
  const int tid = threadIdx.x;
  __shared__ float sX[32][CST + 1];
  const int r = tid >> 3, dg = tid & 7;
  float acc[8];
#pragma unroll
  for (int j = 0; j < 8; j++) acc[j] = 0.f;
  for (int s0 = 0; s0 < CS; s0 += CST) {
    __syncthreads();
    for (int idx = tid; idx < 32 * CST; idx += 256) {
      int rr = idx / CST, cc = idx % CST;
      sX[rr][cc] = __bfloat162float(ctx[(size_t)(b * N_ + n0 + rr) * 960 + choff + s0 + cc]);
    }
    __syncthreads();
    for (int cb = 0; cb < CST; cb += 8) {
      float a[8];
#pragma unroll
      for (int t = 0; t < 8; t++) a[t] = sX[r][cb + t];
#pragma unroll
      for (int j = 0; j < 8; j++)
        acc[j] += dot8(a, w + (size_t)(d0 + dg + 8 * j) * CS + s0 + cb);
    }
  }
  const size_t ob = (size_t)(b * N_ + n0 + r) * 1920 + obase;
#pragma unroll
  for (int j = 0; j < 8; j++) out[ob + d0 + dg + 8 * j] = acc[j];
}

extern "C" void kernel_launch(void* const* d_in, const int* in_sizes, int n_in,
                              void* d_out, int out_size, void* d_ws, size_t ws_size,
                              hipStream_t stream) {
  (void)in_sizes; (void)n_in; (void)out_size; (void)ws_size;
  const float* emb[2][4];
  const float* wq[2][4];
  const float* wo[2][4];
  for (int s = 0; s < 4; s++) {
    emb[0][s] = (const float*)d_in[2 * s];
    emb[1][s] = (const float*)d_in[2 * s + 1];
    wq[0][s] = (const float*)d_in[10 + 4 * s];
    wq[1][s] = (const float*)d_in[11 + 4 * s];
    wo[0][s] = (const float*)d_in[12 + 4 * s];
    wo[1][s] = (const float*)d_in[13 + 4 * s];
  }
  const float* emb_all = (const float*)d_in[8];
  const float* emb_alld = (const float*)d_in[9];
  const float* wkp = (const float*)d_in[26];
  const float* wvp = (const float*)d_in[27];
  const float* wkdp = (const float*)d_in[28];
  const float* wvdp = (const float*)d_in[29];
  float* out = (float*)d_out;

  // workspace layout (bytes): [K V Kd Vd : bf16 4*15.7M] [Q/ctx : bf16 2*15.7M] [probs fp32]
  bf16* w16 = (bf16*)d_ws;
  const size_t KV1 = (size_t)B_ * H_ * N_ * 240;  // 15,728,640 elems
  bf16* Kp = w16;
  bf16* Vp = w16 + KV1;
  bf16* Kdp = w16 + 2 * KV1;
  bf16* Vdp = w16 + 3 * KV1;
  bf16* Qb = w16 + 4 * KV1;  // 2*KV1; Q region, reused as ctx after scores
  float* probs = (float*)(w16 + 6 * KV1);  // 2 * B*H*240*240 fp32
  const int qcum[4] = {0, 16, 48, 112};
  const int chof[4] = {0, 64, 192, 448};
  const size_t PB1 = (size_t)B_ * H_ * 240 * 240;

  const dim3 blk(256);

  // --- Q projections (4 launches, z = modality) ---
  for (int s = 0; s < 4; s++) {
    bf16* q0 = Qb + (size_t)B_ * H_ * N_ * qcum[s];
    bf16* q1 = q0 + KV1;
    dim3 g(N_ / 32, B_ * H_, 2);
    switch (s) {
      case 0: k_proj_q<16><<<g, blk, 0, stream>>>(emb[0][s], wq[0][s], q0, emb[1][s], wq[1][s], q1); break;
      case 1: k_proj_q<32><<<g, blk, 0, stream>>>(emb[0][s], wq[0][s], q0, emb[1][s], wq[1][s], q1); break;
      case 2: k_proj_q<64><<<g, blk, 0, stream>>>(emb[0][s], wq[0][s], q0, emb[1][s], wq[1][s], q1); break;
      case 3: k_proj_q<128><<<g, blk, 0, stream>>>(emb[0][s], wq[0][s], q0, emb[1][s], wq[1][s], q1); break;
    }
  }
  // --- K/V projections (1 launch, z = tensor) ---
  {
    dim3 g(N_ / 32, B_ * H_, 4);
    k_proj_kv<<<g, blk, 0, stream>>>(emb_all, emb_alld, wkp, wvp, wkdp, wvdp, Kp, Vp, Kdp, Vdp);
  }
  // --- scores (4 launches; optical Q x Kd, DSM Q x K) ---
  for (int s = 0; s < 4; s++) {
    const bf16* q0 = Qb + (size_t)B_ * H_ * N_ * qcum[s];
    const bf16* q1 = q0 + KV1;
    float* p0 = probs + (size_t)B_ * H_ * qcum[s] * 240;
    float* p1 = p0 + PB1;
    const int c4 = 16 << s;
    dim3 g(c4 / 16, B_ * H_, 2);
    switch (s) {
      case 0: k_scores<16><<<g, blk, 0, stream>>>(q0, Kdp, p0, q1, Kp, p1); break;
      case 1: k_scores<32><<<g, blk, 0, stream>>>(q0, Kdp, p0, q1, Kp, p1); break;
      case 2: k_scores<64><<<g, blk, 0, stream>>>(q0, Kdp, p0, q1, Kp, p1); break;
      case 3: k_scores<128><<<g, blk, 0, stream>>>(q0, Kdp, p0, q1, Kp, p1); break;
    }
  }
  // --- InstanceNorm + softmax (4 launches) ---
  for (int s = 0; s < 4; s++) {
    float* p0 = probs + (size_t)B_ * H_ * qcum[s] * 240;
    float* p1 = p0 + PB1;
    k_inorm_softmax<<<dim3(B_ * H_, 1, 2), blk, 0, stream>>>(p0, p1, 16 << s);
  }
  // --- PV (4 launches; optical uses Vd, DSM uses V). ctx overlays Q region. ---
  for (int s = 0; s < 4; s++) {
    float* p0 = probs + (size_t)B_ * H_ * qcum[s] * 240;
    float* p1 = p0 + PB1;
    bf16* cx0 = Qb;
    bf16* cx1 = Qb + KV1;
    dim3 g(N_ / 32, B_ * H_, 2);
    switch (s) {
      case 0: k_pv<16><<<g, blk, 0, stream>>>(p0, Vdp, cx0, p1, Vp, cx1, chof[s]); break;
      case 1: k_pv<32><<<g, blk, 0, stream>>>(p0, Vdp, cx0, p1, Vp, cx1, chof[s]); break;
      case 2: k_pv<64><<<g, blk, 0, stream>>>(p0, Vdp, cx0, p1, Vp, cx1, chof[s]); break;
      case 3: k_pv<128><<<g, blk, 0, stream>>>(p0, Vdp, cx0, p1, Vp, cx1, chof[s]); break;
    }
  }
  // --- output projection (4 launches) ---
  for (int s = 0; s < 4; s++) {
    const bf16* cx0 = Qb;
    const bf16* cx1 = Qb + KV1;
    const int cs = 64 << s;
    dim3 g(N_ / 32, B_, 2 * (cs / 64));
    switch (s) {
      case 0: k_wout<64><<<g, blk, 0, stream>>>(cx0, wo[0][s], chof[s], cx1, wo[1][s], 960 + chof[s], out, chof[s]); break;
      case 1: k_wout<128><<<g, blk, 0, stream>>>(cx0, wo[0][s], chof[s], cx1, wo[1][s], 960 + chof[s], out, chof[s]); break;
      case 2: k_wout<256><<<g, blk, 0, stream>>>(cx0, wo[0][s], chof[s], cx1, wo[1][s], 960 + chof[s], out, chof[s]); break;
      case 3: k_wout<512><<<g, blk, 0, stream>>>(cx0, wo[0][s], chof[s], cx1, wo[1][s], 960 + chof[s], out, chof[s]); break;
    }
  }
}

// Round 2
// 1512.200 us; speedup vs baseline: 9.9172x; 9.9172x over previous
//
#include <hip/hip_runtime.h>
#include <hip/hip_bf16.h>

typedef __bf16 bf16_t;
typedef __bf16 bf16x8 __attribute__((ext_vector_type(8)));
typedef float f32x4 __attribute__((ext_vector_type(4)));

static constexpr int B_ = 4, N_ = 4096, H_ = 4;
static constexpr int KS = 40;  // LDS k-stride (bf16): 80 B rows = 5x16B -> aligned b128, spread banks

__device__ __forceinline__ f32x4 mfma_bf16(bf16x8 a, bf16x8 b, f32x4 c) {
  return __builtin_amdgcn_mfma_f32_16x16x32_bf16(a, b, c, 0, 0, 0);
}

__device__ __forceinline__ void st4(bf16_t* d, float4 v) {
  d[0] = (bf16_t)v.x; d[1] = (bf16_t)v.y; d[2] = (bf16_t)v.z; d[3] = (bf16_t)v.w;
}

// kvsplit gather: quarter h, local col c (0..239) -> emb_all column
__device__ __forceinline__ int kvg(int h, int c) {
  if (c < 16)  return h * 16 + c;
  if (c < 48)  return 64 + h * 32 + c - 16;
  if (c < 112) return 192 + h * 64 + c - 48;
  return 448 + h * 128 + c - 112;
}

// ============ K/V projection: Y[bh,n,d] = sum_c gather(emb_all)[bh,n,c] * W[d,c]
// grid (512 m-tiles of 128, 4 tensors), block 256
__global__ __launch_bounds__(256) void k_proj_kv(
    const float* __restrict__ eA, const float* __restrict__ eB,
    const float* __restrict__ wkp, const float* __restrict__ wvp,
    const float* __restrict__ wkdp, const float* __restrict__ wvdp,
    bf16_t* __restrict__ oK, bf16_t* __restrict__ oV,
    bf16_t* __restrict__ oKd, bf16_t* __restrict__ oVd) {
  const int t = blockIdx.y;
  const float* src = (t < 2) ? eA : eB;
  const float* w = (t == 0) ? wkp : (t == 1) ? wvp : (t == 2) ? wkdp : wvdp;
  bf16_t* out = (t == 0) ? oK : (t == 1) ? oV : (t == 2) ? oKd : oVd;
  const int m0 = blockIdx.x * 128;
  const int bh = m0 >> 12, n0 = m0 & 4095;
  const int b = bh >> 2, h = bh & 3;
  const int tid = threadIdx.x, lane = tid & 63, wid = tid >> 6;
  const int l15 = lane & 15, q = lane >> 4;
  __shared__ bf16_t sA[128 * KS];
  __shared__ bf16_t sB[240 * KS];
  const f32x4 fz = {0.f, 0.f, 0.f, 0.f};
  f32x4 acc[2][15];
  for (int i = 0; i < 2; i++) for (int f = 0; f < 15; f++) acc[i][f] = fz;
  const float* srow = src + ((size_t)b * N_ + n0) * 960;
  for (int k0 = 0; k0 < 256; k0 += 32) {
    __syncthreads();
    for (int idx = tid; idx < 1024; idx += 256) {
      int r = idx >> 3, cg = idx & 7, c = k0 + cg * 4;
      float4 v = (c < 240) ? *(const float4*)(srow + (size_t)r * 960 + kvg(h, c))
                           : make_float4(0.f, 0.f, 0.f, 0.f);
      st4(&sA[r * KS + cg * 4], v);
    }
    for (int idx = tid; idx < 1920; idx += 256) {
      int dd = idx >> 3, cg = idx & 7, c = k0 + cg * 4;
      float4 v = (c < 240) ? *(const float4*)(w + dd * 240 + c)
                           : make_float4(0.f, 0.f, 0.f, 0.f);
      st4(&sB[dd * KS + cg * 4], v);
    }
    __syncthreads();
    const bf16_t* ap = &sA[(wid * 32 + l15) * KS + q * 8];
    bf16x8 a0 = *(const bf16x8*)ap;
    bf16x8 a1 = *(const bf16x8*)(ap + 16 * KS);
    for (int f = 0; f < 15; f++) {
      bf16x8 bb = *(const bf16x8*)&sB[(16 * f + l15) * KS + q * 8];
      acc[0][f] = mfma_bf16(a0, bb, acc[0][f]);
      acc[1][f] = mfma_bf16(a1, bb, acc[1][f]);
    }
  }
  bf16_t* orow = out + ((size_t)bh * N_ + n0) * 240;
  for (int i = 0; i < 2; i++)
    for (int f = 0; f < 15; f++)
      for (int r = 0; r < 4; r++) {
        int mm = wid * 32 + 16 * i + q * 4 + r;
        orow[(size_t)mm * 240 + 16 * f + l15] = (bf16_t)acc[i][f][r];
      }
}

// ============ Q projection: Q[bh,n,d] = sum_c emb[b,n,h*C4+c] * wq[h,d,c]
// grid (128 m-tiles of 128 over B*N, 4 h, 2 mods), block 256
template <int C4>
__global__ __launch_bounds__(256) void k_proj_q(
    const float* __restrict__ e0, const float* __restrict__ w0, bf16_t* __restrict__ o0,
    const float* __restrict__ e1, const float* __restrict__ w1, bf16_t* __restrict__ o1) {
  constexpr int KP = (C4 < 32) ? 32 : C4;
  constexpr int NF = C4 / 16;
  const float* emb = blockIdx.z ? e1 : e0;
  const float* wq = blockIdx.z ? w1 : w0;
  bf16_t* qout = blockIdx.z ? o1 : o0;
  const int h = blockIdx.y;
  const int m0 = blockIdx.x * 128;
  const int b = m0 >> 12, n0 = m0 & 4095;
  const int tid = threadIdx.x, lane = tid & 63, wid = tid >> 6;
  const int l15 = lane & 15, q = lane >> 4;
  __shared__ bf16_t sA[128 * KS];
  __shared__ bf16_t sB[C4 * KS];
  const f32x4 fz = {0.f, 0.f, 0.f, 0.f};
  f32x4 acc[2][NF];
  for (int i = 0; i < 2; i++) for (int f = 0; f < NF; f++) acc[i][f] = fz;
  const float* srow = emb + ((size_t)b * N_ + n0) * (H_ * C4) + h * C4;
  const float* wb = wq + h * C4 * C4;
  for (int k0 = 0; k0 < KP; k0 += 32) {
    __syncthreads();
    for (int idx = tid; idx < 1024; idx += 256) {
      int r = idx >> 3, cg = idx & 7, c = k0 + cg * 4;
      float4 v = (c < C4) ? *(const float4*)(srow + (size_t)r * (H_ * C4) + c)
                          : make_float4(0.f, 0.f, 0.f, 0.f);
      st4(&sA[r * KS + cg * 4], v);
    }
    for (int idx = tid; idx < C4 * 8; idx += 256) {
      int dd = idx >> 3, cg = idx & 7, c = k0 + cg * 4;
      float4 v = (c < C4) ? *(const float4*)(wb + dd * C4 + c)
                          : make_float4(0.f, 0.f, 0.f, 0.f);
      st4(&sB[dd * KS + cg * 4], v);
    }
    __syncthreads();
    const bf16_t* ap = &sA[(wid * 32 + l15) * KS + q * 8];
    bf16x8 a0 = *(const bf16x8*)ap;
    bf16x8 a1 = *(const bf16x8*)(ap + 16 * KS);
    for (int f = 0; f < NF; f++) {
      bf16x8 bb = *(const bf16x8*)&sB[(16 * f + l15) * KS + q * 8];
      acc[0][f] = mfma_bf16(a0, bb, acc[0][f]);
      acc[1][f] = mfma_bf16(a1, bb, acc[1][f]);
    }
  }
  bf16_t* orow = qout + (((size_t)b * H_ + h) * N_ + n0) * C4;
  for (int i = 0; i < 2; i++)
    for (int f = 0; f < NF; f++)
      for (int r = 0; r < 4; r++) {
        int mm = wid * 32 + 16 * i + q * 4 + r;
        orow[(size_t)mm * C4 + 16 * f + l15] = (bf16_t)acc[i][f][r];
      }
}

// ============ scores: S[c,k] += (1/sqrt960) sum_{n in chunk} Q[n,c]*K[n,k]
// grid (C4/16, 16 bh, 2 mods * 8 n-chunks), block 256; fp32 atomicAdd epilogue
template <int C4>
__global__ __launch_bounds__(256) void k_scores(
    const bf16_t* __restrict__ q0, const bf16_t* __restrict__ k0p, float* __restrict__ s0,
    const bf16_t* __restrict__ q1, const bf16_t* __restrict__ k1p, float* __restrict__ s1) {
  const int mod = blockIdx.z >> 3, chunk = blockIdx.z & 7;
  const bf16_t* qp = mod ? q1 : q0;
  const bf16_t* kp = mod ? k1p : k0p;
  float* sc = mod ? s1 : s0;
  const int bh = blockIdx.y;
  const int c0 = blockIdx.x * 16;
  const int nbase = chunk * 512;
  const int tid = threadIdx.x, lane = tid & 63, wid = tid >> 6;
  const int l15 = lane & 15, q = lane >> 4;
  __shared__ bf16_t sQ[16 * KS];
  __shared__ bf16_t sK[240 * KS];
  const f32x4 fz = {0.f, 0.f, 0.f, 0.f};
  f32x4 acc[4] = {fz, fz, fz, fz};
  for (int k0 = 0; k0 < 512; k0 += 32) {
    __syncthreads();
    const size_t nb = (size_t)bh * N_ + nbase + k0;
    for (int idx = tid; idx < 512; idx += 256) {  // Q^T stage (32n x 16c)
      int ni = idx >> 4, ci = idx & 15;
      sQ[ci * KS + ni] = qp[(nb + ni) * C4 + c0 + ci];
    }
    for (int idx = tid; idx < 7680; idx += 256) {  // K^T stage (32n x 240k)
      int ni = idx / 240, kk = idx - 240 * ni;
      sK[kk * KS + ni] = kp[(nb + ni) * 240 + kk];
    }
    __syncthreads();
    bf16x8 af = *(const bf16x8*)&sQ[l15 * KS + q * 8];
    for (int j = 0; j < 4; j++) {
      int f = wid + 4 * j;
      if (f < 15) {
        bf16x8 bb = *(const bf16x8*)&sK[(16 * f + l15) * KS + q * 8];
        acc[j] = mfma_bf16(af, bb, acc[j]);
      }
    }
  }
  const float rs = 0.0322748612183951f;  // 1/sqrt(960)
  float* sb = sc + (size_t)bh * C4 * 240;
  for (int j = 0; j < 4; j++) {
    int f = wid + 4 * j;
    if (f < 15)
      for (int r = 0; r < 4; r++)
        atomicAdd(&sb[(size_t)(c0 + q * 4 + r) * 240 + 16 * f + l15], acc[j][r] * rs);
  }
}

// ============ InstanceNorm over (c,k) per (b,h), then softmax over k (240)
__global__ __launch_bounds__(256) void k_inorm_softmax(float* __restrict__ p0,
                                                       float* __restrict__ p1, int c4) {
  float* p = (blockIdx.z ? p1 : p0) + (size_t)blockIdx.x * c4 * 240;
  const int tid = threadIdx.x;
  const int tot = c4 * 240;
  float s = 0.f, s2 = 0.f;
  for (int idx = tid; idx < tot; idx += 256) {
    float v = p[idx];
    s += v; s2 += v * v;
  }
#pragma unroll
  for (int off = 32; off > 0; off >>= 1) {
    s += __shfl_xor(s, off);
    s2 += __shfl_xor(s2, off);
  }
  __shared__ float rsum[4], rsum2[4], smv[2];
  const int wid = tid >> 6, lane = tid & 63;
  if (lane == 0) { rsum[wid] = s; rsum2[wid] = s2; }
  __syncthreads();
  if (tid == 0) {
    float ts = rsum[0] + rsum[1] + rsum[2] + rsum[3];
    float ts2 = rsum2[0] + rsum2[1] + rsum2[2] + rsum2[3];
    float mean = ts / tot;
    float var = ts2 / tot - mean * mean;
    smv[0] = mean; smv[1] = rsqrtf(var + 1e-5f);
  }
  __syncthreads();
  const float mean = smv[0], rstd = smv[1];
  for (int c = wid; c < c4; c += 4) {
    float* row = p + (size_t)c * 240;
    float x[4]; float mx = -1e30f;
#pragma unroll
    for (int t = 0; t < 4; t++) {
      int k = lane + 64 * t;
      x[t] = (k < 240) ? (row[k] - mean) * rstd : -1e30f;
      mx = fmaxf(mx, x[t]);
    }
#pragma unroll
    for (int off = 32; off > 0; off >>= 1) mx = fmaxf(mx, __shfl_xor(mx, off));
    float e[4], sum = 0.f;
#pragma unroll
    for (int t = 0; t < 4; t++) {
      int k = lane + 64 * t;
      e[t] = (k < 240) ? expf(x[t] - mx) : 0.f;
      sum += e[t];
    }
#pragma unroll
    for (int off = 32; off > 0; off >>= 1) sum += __shfl_xor(sum, off);
    const float inv = 1.f / sum;
#pragma unroll
    for (int t = 0; t < 4; t++) {
      int k = lane + 64 * t;
      if (k < 240) row[k] = e[t] * inv;
    }
  }
}

// ============ PV: ctx[b,n,chof+h*C4+c] = sum_k P[c,k] * V[bh,n,k]
// grid (32 n-tiles of 128, 16 bh, 2 mods), block 256
template <int C4>
__global__ __launch_bounds__(256) void k_pv(
    const float* __restrict__ p0, const bf16_t* __restrict__ v0, bf16_t* __restrict__ c0p,
    const float* __restrict__ p1, const bf16_t* __restrict__ v1, bf16_t* __restrict__ c1p,
    int chof) {
  constexpr int NF = C4 / 16;
  const float* pr = blockIdx.z ? p1 : p0;
  const bf16_t* v = blockIdx.z ? v1 : v0;
  bf16_t* ctx = blockIdx.z ? c1p : c0p;
  const int bh = blockIdx.y, b = bh >> 2, h = bh & 3;
  const int n0 = blockIdx.x * 128;
  const int tid = threadIdx.x, lane = tid & 63, wid = tid >> 6;
  const int l15 = lane & 15, q = lane >> 4;
  __shared__ bf16_t sV[128 * KS];
  __shared__ bf16_t sP[C4 * KS];
  const f32x4 fz = {0.f, 0.f, 0.f, 0.f};
  f32x4 acc[2][NF];
  for (int i = 0; i < 2; i++) for (int f = 0; f < NF; f++) acc[i][f] = fz;
  const bf16_t* vrow = v + ((size_t)bh * N_ + n0) * 240;
  const float* pb = pr + (size_t)bh * C4 * 240;
  for (int k0 = 0; k0 < 256; k0 += 32) {
    __syncthreads();
    for (int idx = tid; idx < 1024; idx += 256) {
      int r = idx >> 3, cg = idx & 7, k = k0 + cg * 4;
      if (k < 240)
        *(uint2*)&sV[r * KS + cg * 4] = *(const uint2*)(vrow + (size_t)r * 240 + k);
      else
        *(uint2*)&sV[r * KS + cg * 4] = make_uint2(0u, 0u);
    }
    for (int idx = tid; idx < C4 * 8; idx += 256) {
      int cc = idx >> 3, cg = idx & 7, k = k0 + cg * 4;
      float4 val = (k < 240) ? *(const float4*)(pb + (size_t)cc * 240 + k)
                             : make_float4(0.f, 0.f, 0.f, 0.f);
      st4(&sP[cc * KS + cg * 4], val);
    }
    __syncthreads();
    const bf16_t* ap = &sV[(wid * 32 + l15) * KS + q * 8];
    bf16x8 a0 = *(const bf16x8*)ap;
    bf16x8 a1 = *(const bf16x8*)(ap + 16 * KS);
    for (int f = 0; f < NF; f++) {
      bf16x8 bb = *(const bf16x8*)&sP[(16 * f + l15) * KS + q * 8];
      acc[0][f] = mfma_bf16(a0, bb, acc[0][f]);
      acc[1][f] = mfma_bf16(a1, bb, acc[1][f]);
    }
  }
  bf16_t* crow = ctx + ((size_t)b * N_ + n0) * 960 + chof + h * C4;
  for (int i = 0; i < 2; i++)
    for (int f = 0; f < NF; f++)
      for (int r = 0; r < 4; r++) {
        int mm = wid * 32 + 16 * i + q * 4 + r;
        crow[(size_t)mm * 960 + 16 * f + l15] = (bf16_t)acc[i][f][r];
      }
}

// ============ out[b,n,obase+d] = sum_c ctx[b,n,chof+c] * w[d,c]   (fp32 out)
// grid (128 m-tiles of 128 over B*N, 1, 2*DB), block 256
template <int CS>
__global__ __launch_bounds__(256) void k_wout(
    const bf16_t* __restrict__ c0p, const float* __restrict__ w0, int ob0,
    const bf16_t* __restrict__ c1p, const float* __restrict__ w1, int ob1,
    float* __restrict__ out, int chof) {
  constexpr int DT = (CS < 128) ? CS : 128;
  constexpr int NF = DT / 16;
  constexpr int DB = CS / DT;
  const int mod = blockIdx.z / DB, dch = blockIdx.z % DB;
  const bf16_t* ctx = mod ? c1p : c0p;
  const float* w = mod ? w1 : w0;
  const int obase = (mod ? ob1 : ob0) + dch * DT;
  const int m0 = blockIdx.x * 128;
  const int b = m0 >> 12, n0 = m0 & 4095;
  const int tid = threadIdx.x, lane = tid & 63, wid = tid >> 6;
  const int l15 = lane & 15, q = lane >> 4;
  __shared__ bf16_t sA[128 * KS];
  __shared__ bf16_t sB[DT * KS];
  const f32x4 fz = {0.f, 0.f, 0.f, 0.f};
  f32x4 acc[2][NF];
  for (int i = 0; i < 2; i++) for (int f = 0; f < NF; f++) acc[i][f] = fz;
  const bf16_t* arow = ctx + ((size_t)b * N_ + n0) * 960 + chof;
  const float* wb = w + (size_t)dch * DT * CS;
  for (int k0 = 0; k0 < CS; k0 += 32) {
    __syncthreads();
    for (int idx = tid; idx < 1024; idx += 256) {
      int r = idx >> 3, cg = idx & 7, k = k0 + cg * 4;
      *(uint2*)&sA[r * KS + cg * 4] = *(const uint2*)(arow + (size_t)r * 960 + k);
    }
    for (int idx = tid; idx < DT * 8; idx += 256) {
      int dd = idx >> 3, cg = idx & 7, k = k0 + cg * 4;
      float4 val = *(const float4*)(wb + (size_t)dd * CS + k);
      st4(&sB[dd * KS + cg * 4], val);
    }
    __syncthreads();
    const bf16_t* ap = &sA[(wid * 32 + l15) * KS + q * 8];
    bf16x8 a0 = *(const bf16x8*)ap;
    bf16x8 a1 = *(const bf16x8*)(ap + 16 * KS);
    for (int f = 0; f < NF; f++) {
      bf16x8 bb = *(const bf16x8*)&sB[(16 * f + l15) * KS + q * 8];
      acc[0][f] = mfma_bf16(a0, bb, acc[0][f]);
      acc[1][f] = mfma_bf16(a1, bb, acc[1][f]);
    }
  }
  float* orow = out + ((size_t)b * N_ + n0) * 1920 + obase;
  for (int i = 0; i < 2; i++)
    for (int f = 0; f < NF; f++)
      for (int r = 0; r < 4; r++) {
        int mm = wid * 32 + 16 * i + q * 4 + r;
        orow[(size_t)mm * 1920 + 16 * f + l15] = acc[i][f][r];
      }
}

extern "C" void kernel_launch(void* const* d_in, const int* in_sizes, int n_in,
                              void* d_out, int out_size, void* d_ws, size_t ws_size,
                              hipStream_t stream) {
  (void)in_sizes; (void)n_in; (void)out_size; (void)ws_size;
  const float* emb[2][4];
  const float* wq[2][4];
  const float* wo[2][4];
  for (int s = 0; s < 4; s++) {
    emb[0][s] = (const float*)d_in[2 * s];
    emb[1][s] = (const float*)d_in[2 * s + 1];
    wq[0][s] = (const float*)d_in[10 + 4 * s];
    wq[1][s] = (const float*)d_in[11 + 4 * s];
    wo[0][s] = (const float*)d_in[12 + 4 * s];
    wo[1][s] = (const float*)d_in[13 + 4 * s];
  }
  const float* emb_all = (const float*)d_in[8];
  const float* emb_alld = (const float*)d_in[9];
  const float* wkp = (const float*)d_in[26];
  const float* wvp = (const float*)d_in[27];
  const float* wkdp = (const float*)d_in[28];
  const float* wvdp = (const float*)d_in[29];
  float* out = (float*)d_out;

  bf16_t* w16 = (bf16_t*)d_ws;
  const size_t KV1 = (size_t)B_ * H_ * N_ * 240;  // 15,728,640
  bf16_t* Kp = w16;
  bf16_t* Vp = w16 + KV1;
  bf16_t* Kdp = w16 + 2 * KV1;
  bf16_t* Vdp = w16 + 3 * KV1;
  bf16_t* Qb = w16 + 4 * KV1;              // Q region; reused as ctx after scores
  float* probs = (float*)(w16 + 6 * KV1);  // 2 * B*H*240*240 fp32
  const int qcum[4] = {0, 16, 48, 112};
  const int chof[4] = {0, 64, 192, 448};
  const size_t PB1 = (size_t)B_ * H_ * 240 * 240;
  const dim3 blk(256);

  // probs accumulated via atomicAdd -> zero it (ws is poisoned each call)
  hipMemsetAsync(probs, 0, 2 * PB1 * sizeof(float), stream);

  // --- Q projections ---
  for (int s = 0; s < 4; s++) {
    bf16_t* q0 = Qb + (size_t)B_ * H_ * N_ * qcum[s];
    bf16_t* q1 = q0 + KV1;
    dim3 g(B_ * N_ / 128, H_, 2);
    switch (s) {
      case 0: k_proj_q<16><<<g, blk, 0, stream>>>(emb[0][s], wq[0][s], q0, emb[1][s], wq[1][s], q1); break;
      case 1: k_proj_q<32><<<g, blk, 0, stream>>>(emb[0][s], wq[0][s], q0, emb[1][s], wq[1][s], q1); break;
      case 2: k_proj_q<64><<<g, blk, 0, stream>>>(emb[0][s], wq[0][s], q0, emb[1][s], wq[1][s], q1); break;
      case 3: k_proj_q<128><<<g, blk, 0, stream>>>(emb[0][s], wq[0][s], q0, emb[1][s], wq[1][s], q1); break;
    }
  }
  // --- K/V projections ---
  k_proj_kv<<<dim3(B_ * H_ * N_ / 128, 4), blk, 0, stream>>>(
      emb_all, emb_alld, wkp, wvp, wkdp, wvdp, Kp, Vp, Kdp, Vdp);
  // --- scores (optical Q x Kd, DSM Q x K); split-K over n, atomicAdd ---
  for (int s = 0; s < 4; s++) {
    const bf16_t* q0 = Qb + (size_t)B_ * H_ * N_ * qcum[s];
    const bf16_t* q1 = q0 + KV1;
    float* p0 = probs + (size_t)B_ * H_ * qcum[s] * 240;
    float* p1 = p0 + PB1;
    const int c4 = 16 << s;
    dim3 g(c4 / 16, B_ * H_, 16);
    switch (s) {
      case 0: k_scores<16><<<g, blk, 0, stream>>>(q0, Kdp, p0, q1, Kp, p1); break;
      case 1: k_scores<32><<<g, blk, 0, stream>>>(q0, Kdp, p0, q1, Kp, p1); break;
      case 2: k_scores<64><<<g, blk, 0, stream>>>(q0, Kdp, p0, q1, Kp, p1); break;
      case 3: k_scores<128><<<g, blk, 0, stream>>>(q0, Kdp, p0, q1, Kp, p1); break;
    }
  }
  // --- InstanceNorm + softmax ---
  for (int s = 0; s < 4; s++) {
    float* p0 = probs + (size_t)B_ * H_ * qcum[s] * 240;
    float* p1 = p0 + PB1;
    k_inorm_softmax<<<dim3(B_ * H_, 1, 2), blk, 0, stream>>>(p0, p1, 16 << s);
  }
  // --- PV (optical uses Vd, DSM uses V); ctx overlays Q region ---
  for (int s = 0; s < 4; s++) {
    float* p0 = probs + (size_t)B_ * H_ * qcum[s] * 240;
    float* p1 = p0 + PB1;
    bf16_t* cx0 = Qb;
    bf16_t* cx1 = Qb + KV1;
    dim3 g(N_ / 128, B_ * H_, 2);
    switch (s) {
      case 0: k_pv<16><<<g, blk, 0, stream>>>(p0, Vdp, cx0, p1, Vp, cx1, chof[s]); break;
      case 1: k_pv<32><<<g, blk, 0, stream>>>(p0, Vdp, cx0, p1, Vp, cx1, chof[s]); break;
      case 2: k_pv<64><<<g, blk, 0, stream>>>(p0, Vdp, cx0, p1, Vp, cx1, chof[s]); break;
      case 3: k_pv<128><<<g, blk, 0, stream>>>(p0, Vdp, cx0, p1, Vp, cx1, chof[s]); break;
    }
  }
  // --- output projection ---
  for (int s = 0; s < 4; s++) {
    const bf16_t* cx0 = Qb;
    const bf16_t* cx1 = Qb + KV1;
    const int cs = 64 << s;
    const int db = (cs < 128) ? 1 : cs / 128;
    dim3 g(B_ * N_ / 128, 1, 2 * db);
    switch (s) {
      case 0: k_wout<64><<<g, blk, 0, stream>>>(cx0, wo[0][s], chof[s], cx1, wo[1][s], 960 + chof[s], out, chof[s]); break;
      case 1: k_wout<128><<<g, blk, 0, stream>>>(cx0, wo[0][s], chof[s], cx1, wo[1][s], 960 + chof[s], out, chof[s]); break;
      case 2: k_wout<256><<<g, blk, 0, stream>>>(cx0, wo[0][s], chof[s], cx1, wo[1][s], 960 + chof[s], out, chof[s]); break;
      case 3: k_wout<512><<<g, blk, 0, stream>>>(cx0, wo[0][s], chof[s], cx1, wo[1][s], 960 + chof[s], out, chof[s]); break;
    }
  }
}

// Round 3
// 1273.726 us; speedup vs baseline: 11.7740x; 1.1872x over previous
//
#include <hip/hip_runtime.h>
#include <hip/hip_bf16.h>

typedef __bf16 bf16_t;
typedef __bf16 bf16x8 __attribute__((ext_vector_type(8)));
typedef float f32x4 __attribute__((ext_vector_type(4)));

static constexpr int B_ = 4, N_ = 4096, H_ = 4;
static constexpr int KS = 40;  // LDS k-stride (bf16): 80 B rows, 16B-aligned b128, 2-way max on reads

__device__ __forceinline__ f32x4 mfma_bf16(bf16x8 a, bf16x8 b, f32x4 c) {
  return __builtin_amdgcn_mfma_f32_16x16x32_bf16(a, b, c, 0, 0, 0);
}

// convert float4 -> 4 bf16 in registers, single 8 B LDS store (no scalar ds_write_b16)
__device__ __forceinline__ void stpk4(bf16_t* d, float4 v) {
  bf16_t t[4] = {(bf16_t)v.x, (bf16_t)v.y, (bf16_t)v.z, (bf16_t)v.w};
  *(uint2*)d = *(const uint2*)t;
}
__device__ __forceinline__ void stz8(bf16_t* d) { *(uint2*)d = make_uint2(0u, 0u); }

// kvsplit gather: quarter h, local col c (0..239) -> emb_all column
__device__ __forceinline__ int kvg(int h, int c) {
  if (c < 16)  return h * 16 + c;
  if (c < 48)  return 64 + h * 32 + c - 16;
  if (c < 112) return 192 + h * 64 + c - 48;
  return 448 + h * 128 + c - 112;
}

// ============ weight pre-convert fp32 -> bf16 (one pass, ~230k f4 items)
__global__ __launch_bounds__(256) void k_prep_w(
    const float* __restrict__ wk, const float* __restrict__ wv,
    const float* __restrict__ wkd, const float* __restrict__ wvd,
    const float* __restrict__ wo00, const float* __restrict__ wo01,
    const float* __restrict__ wo02, const float* __restrict__ wo03,
    const float* __restrict__ wo10, const float* __restrict__ wo11,
    const float* __restrict__ wo12, const float* __restrict__ wo13,
    bf16_t* __restrict__ Wkvb, bf16_t* __restrict__ Wob) {
  const float* wkv[4] = {wk, wv, wkd, wvd};
  const float* wo[2][4] = {{wo00, wo01, wo02, wo03}, {wo10, wo11, wo12, wo13}};
  const int soff_f4[5] = {0, 1024, 5120, 21504, 87040};
  for (int i = blockIdx.x * 256 + threadIdx.x; i < 231680; i += gridDim.x * 256) {
    if (i < 57600) {  // kv weights: 4 x 14400 f4
      int t = i / 14400, r = i - t * 14400;
      float4 v = *(const float4*)(wkv[t] + r * 4);
      stpk4(Wkvb + (size_t)t * 57600 + r * 4, v);
    } else {  // wout: 2 x 87040 f4
      int j = i - 57600;
      int mod = j / 87040, jr = j - mod * 87040;
      int s = (jr < 1024) ? 0 : (jr < 5120) ? 1 : (jr < 21504) ? 2 : 3;
      float4 v = *(const float4*)(wo[mod][s] + (jr - soff_f4[s]) * 4);
      stpk4(Wob + (size_t)mod * 348160 + jr * 4, v);
    }
  }
}

// ============ Q projection: Q[bh,n,d] = sum_c emb[b,n,h*C4+c] * wq[h,d,c]  (n-major out)
template <int C4>
__global__ __launch_bounds__(256) void k_proj_q(
    const float* __restrict__ e0, const float* __restrict__ w0, bf16_t* __restrict__ o0,
    const float* __restrict__ e1, const float* __restrict__ w1, bf16_t* __restrict__ o1) {
  constexpr int KP = (C4 < 32) ? 32 : C4;
  constexpr int NF = C4 / 16;
  const float* emb = blockIdx.z ? e1 : e0;
  const float* wq = blockIdx.z ? w1 : w0;
  bf16_t* qout = blockIdx.z ? o1 : o0;
  const int h = blockIdx.y;
  const int m0 = blockIdx.x * 128;
  const int b = m0 >> 12, n0 = m0 & 4095;
  const int tid = threadIdx.x, lane = tid & 63, wid = tid >> 6;
  const int l15 = lane & 15, q = lane >> 4;
  __shared__ bf16_t sA[128 * KS];
  __shared__ bf16_t sB[C4 * KS];
  const f32x4 fz = {0.f, 0.f, 0.f, 0.f};
  f32x4 acc[2][NF];
  for (int i = 0; i < 2; i++) for (int f = 0; f < NF; f++) acc[i][f] = fz;
  const float* srow = emb + ((size_t)b * N_ + n0) * (H_ * C4) + h * C4;
  const float* wb = wq + h * C4 * C4;
  for (int k0 = 0; k0 < KP; k0 += 32) {
    __syncthreads();
    for (int idx = tid; idx < 1024; idx += 256) {
      int r = idx >> 3, cg = idx & 7, c = k0 + cg * 4;
      if (c < C4) stpk4(&sA[r * KS + cg * 4], *(const float4*)(srow + (size_t)r * (H_ * C4) + c));
      else stz8(&sA[r * KS + cg * 4]);
    }
    for (int idx = tid; idx < C4 * 8; idx += 256) {
      int dd = idx >> 3, cg = idx & 7, c = k0 + cg * 4;
      if (c < C4) stpk4(&sB[dd * KS + cg * 4], *(const float4*)(wb + dd * C4 + c));
      else stz8(&sB[dd * KS + cg * 4]);
    }
    __syncthreads();
    const bf16_t* ap = &sA[(wid * 32 + l15) * KS + q * 8];
    bf16x8 a0 = *(const bf16x8*)ap;
    bf16x8 a1 = *(const bf16x8*)(ap + 16 * KS);
    for (int f = 0; f < NF; f++) {
      bf16x8 bb = *(const bf16x8*)&sB[(16 * f + l15) * KS + q * 8];
      acc[0][f] = mfma_bf16(a0, bb, acc[0][f]);
      acc[1][f] = mfma_bf16(a1, bb, acc[1][f]);
    }
  }
  bf16_t* orow = qout + (((size_t)b * H_ + h) * N_ + n0) * C4;
  for (int i = 0; i < 2; i++)
    for (int f = 0; f < NF; f++)
      for (int r = 0; r < 4; r++) {
        int mm = wid * 32 + 16 * i + q * 4 + r;
        orow[(size_t)mm * C4 + 16 * f + l15] = (bf16_t)acc[i][f][r];
      }
}

// ============ K/V projection. t=0:K^T t=1:V t=2:Kd^T t=3:Vd
// K stored transposed [bh][240][4096] (packed b64 stores); V n-major [bh][n][240]
__global__ __launch_bounds__(256) void k_proj_kv(
    const float* __restrict__ eA, const float* __restrict__ eB,
    const bf16_t* __restrict__ Wkvb,
    bf16_t* __restrict__ Kt0, bf16_t* __restrict__ V0,
    bf16_t* __restrict__ Kt1, bf16_t* __restrict__ V1) {
  const int t = blockIdx.y;
  const float* src = (t < 2) ? eA : eB;
  const bf16_t* w = Wkvb + (size_t)t * 57600;
  const int m0 = blockIdx.x * 128;
  const int bh = m0 >> 12, n0 = m0 & 4095;
  const int b = bh >> 2, h = bh & 3;
  const int tid = threadIdx.x, lane = tid & 63, wid = tid >> 6;
  const int l15 = lane & 15, q = lane >> 4;
  __shared__ bf16_t sA[128 * KS];
  __shared__ bf16_t sB[240 * KS];
  const f32x4 fz = {0.f, 0.f, 0.f, 0.f};
  f32x4 acc[2][15];
  for (int i = 0; i < 2; i++) for (int f = 0; f < 15; f++) acc[i][f] = fz;
  const float* srow = src + ((size_t)b * N_ + n0) * 960;
  for (int k0 = 0; k0 < 256; k0 += 32) {
    __syncthreads();
    for (int idx = tid; idx < 1024; idx += 256) {  // A: gather + convert, packed b64
      int r = idx >> 3, cg = idx & 7, c = k0 + cg * 4;
      if (c < 240) stpk4(&sA[r * KS + cg * 4], *(const float4*)(srow + (size_t)r * 960 + kvg(h, c)));
      else stz8(&sA[r * KS + cg * 4]);
    }
    for (int idx = tid; idx < 960; idx += 256) {  // B: pure uint4 copies (bf16 weights)
      int dd = idx >> 2, g = idx & 3, c = k0 + g * 8;
      if (c < 240) *(uint4*)&sB[dd * KS + g * 8] = *(const uint4*)(w + dd * 240 + c);
      else *(uint4*)&sB[dd * KS + g * 8] = make_uint4(0u, 0u, 0u, 0u);
    }
    __syncthreads();
    const bf16_t* ap = &sA[(wid * 32 + l15) * KS + q * 8];
    bf16x8 a0 = *(const bf16x8*)ap;
    bf16x8 a1 = *(const bf16x8*)(ap + 16 * KS);
    for (int f = 0; f < 15; f++) {
      bf16x8 bb = *(const bf16x8*)&sB[(16 * f + l15) * KS + q * 8];
      acc[0][f] = mfma_bf16(a0, bb, acc[0][f]);
      acc[1][f] = mfma_bf16(a1, bb, acc[1][f]);
    }
  }
  if ((t & 1) == 0) {  // K^T: rows k=16f+l15, cols n; 4 consecutive n packed in b64
    bf16_t* kt = (t == 0) ? Kt0 : Kt1;
    for (int i = 0; i < 2; i++)
      for (int f = 0; f < 15; f++) {
        bf16_t pk[4];
        for (int r = 0; r < 4; r++) pk[r] = (bf16_t)acc[i][f][r];
        bf16_t* dst = kt + ((size_t)bh * 240 + 16 * f + l15) * 4096 + n0 + wid * 32 + 16 * i + q * 4;
        *(uint2*)dst = *(const uint2*)pk;
      }
  } else {  // V n-major
    bf16_t* vv = (t == 1) ? V0 : V1;
    bf16_t* orow = vv + ((size_t)bh * N_ + n0) * 240;
    for (int i = 0; i < 2; i++)
      for (int f = 0; f < 15; f++)
        for (int r = 0; r < 4; r++) {
          int mm = wid * 32 + 16 * i + q * 4 + r;
          orow[(size_t)mm * 240 + 16 * f + l15] = (bf16_t)acc[i][f][r];
        }
  }
}

// ============ scores: S[c,k] += (1/sqrt960) sum_{n chunk} Q[n,c]*K^T[k,n]
// grid (C4/16, 16 bh, 2 mods * 8 chunks); K^T staged via uint4, Q via small scalar transpose
template <int C4>
__global__ __launch_bounds__(256) void k_scores(
    const bf16_t* __restrict__ q0, const bf16_t* __restrict__ kt0, float* __restrict__ s0,
    const bf16_t* __restrict__ q1, const bf16_t* __restrict__ kt1, float* __restrict__ s1) {
  const int mod = blockIdx.z >> 3, chunk = blockIdx.z & 7;
  const bf16_t* qp = mod ? q1 : q0;
  const bf16_t* ktp = mod ? kt1 : kt0;
  float* sc = mod ? s1 : s0;
  const int bh = blockIdx.y;
  const int c0 = blockIdx.x * 16;
  const int tid = threadIdx.x, lane = tid & 63, wid = tid >> 6;
  const int l15 = lane & 15, q = lane >> 4;
  __shared__ bf16_t sQ[16 * KS];
  __shared__ bf16_t sK[240 * KS];
  const f32x4 fz = {0.f, 0.f, 0.f, 0.f};
  f32x4 acc[4] = {fz, fz, fz, fz};
  const bf16_t* ktb = ktp + (size_t)bh * 240 * 4096 + chunk * 512;
  const bf16_t* qb = qp + ((size_t)bh * N_ + chunk * 512) * C4 + c0;
  for (int k0 = 0; k0 < 512; k0 += 32) {
    __syncthreads();
    for (int idx = tid; idx < 512; idx += 256) {  // Q^T small transpose (scalar, cheap)
      int ni = idx >> 4, ci = idx & 15;
      sQ[ci * KS + ni] = qb[(size_t)(k0 + ni) * C4 + ci];
    }
    for (int idx = tid; idx < 960; idx += 256) {  // K^T contiguous uint4
      int kk = idx >> 2, g = idx & 3;
      *(uint4*)&sK[kk * KS + g * 8] = *(const uint4*)(ktb + (size_t)kk * 4096 + k0 + g * 8);
    }
    __syncthreads();
    bf16x8 af = *(const bf16x8*)&sQ[l15 * KS + q * 8];
    for (int j = 0; j < 4; j++) {
      int f = wid + 4 * j;
      if (f < 15) {
        bf16x8 bb = *(const bf16x8*)&sK[(16 * f + l15) * KS + q * 8];
        acc[j] = mfma_bf16(af, bb, acc[j]);
      }
    }
  }
  const float rs = 0.0322748612183951f;  // 1/sqrt(960)
  float* sb = sc + (size_t)bh * C4 * 240;
  for (int j = 0; j < 4; j++) {
    int f = wid + 4 * j;
    if (f < 15)
      for (int r = 0; r < 4; r++)
        atomicAdd(&sb[(size_t)(c0 + q * 4 + r) * 240 + 16 * f + l15], acc[j][r] * rs);
  }
}

// ============ InstanceNorm over (c,k) per (b,h), then softmax over k (240)
__global__ __launch_bounds__(256) void k_inorm_softmax(float* __restrict__ p0,
                                                       float* __restrict__ p1, int c4) {
  float* p = (blockIdx.z ? p1 : p0) + (size_t)blockIdx.x * c4 * 240;
  const int tid = threadIdx.x;
  const int tot = c4 * 240;
  float s = 0.f, s2 = 0.f;
  for (int idx = tid; idx < tot; idx += 256) {
    float v = p[idx];
    s += v; s2 += v * v;
  }
#pragma unroll
  for (int off = 32; off > 0; off >>= 1) {
    s += __shfl_xor(s, off);
    s2 += __shfl_xor(s2, off);
  }
  __shared__ float rsum[4], rsum2[4], smv[2];
  const int wid = tid >> 6, lane = tid & 63;
  if (lane == 0) { rsum[wid] = s; rsum2[wid] = s2; }
  __syncthreads();
  if (tid == 0) {
    float ts = rsum[0] + rsum[1] + rsum[2] + rsum[3];
    float ts2 = rsum2[0] + rsum2[1] + rsum2[2] + rsum2[3];
    float mean = ts / tot;
    float var = ts2 / tot - mean * mean;
    smv[0] = mean; smv[1] = rsqrtf(var + 1e-5f);
  }
  __syncthreads();
  const float mean = smv[0], rstd = smv[1];
  for (int c = wid; c < c4; c += 4) {
    float* row = p + (size_t)c * 240;
    float x[4]; float mx = -1e30f;
#pragma unroll
    for (int t = 0; t < 4; t++) {
      int k = lane + 64 * t;
      x[t] = (k < 240) ? (row[k] - mean) * rstd : -1e30f;
      mx = fmaxf(mx, x[t]);
    }
#pragma unroll
    for (int off = 32; off > 0; off >>= 1) mx = fmaxf(mx, __shfl_xor(mx, off));
    float e[4], sum = 0.f;
#pragma unroll
    for (int t = 0; t < 4; t++) {
      int k = lane + 64 * t;
      e[t] = (k < 240) ? expf(x[t] - mx) : 0.f;
      sum += e[t];
    }
#pragma unroll
    for (int off = 32; off > 0; off >>= 1) sum += __shfl_xor(sum, off);
    const float inv = 1.f / sum;
#pragma unroll
    for (int t = 0; t < 4; t++) {
      int k = lane + 64 * t;
      if (k < 240) row[k] = e[t] * inv;
    }
  }
}

// ============ PV: ctx[b,n,chof+h*C4+c] = sum_k P[c,k] * V[bh,n,k]
template <int C4>
__global__ __launch_bounds__(256) void k_pv(
    const float* __restrict__ p0, const bf16_t* __restrict__ v0, bf16_t* __restrict__ c0p,
    const float* __restrict__ p1, const bf16_t* __restrict__ v1, bf16_t* __restrict__ c1p,
    int chof) {
  constexpr int NF = C4 / 16;
  const float* pr = blockIdx.z ? p1 : p0;
  const bf16_t* v = blockIdx.z ? v1 : v0;
  bf16_t* ctx = blockIdx.z ? c1p : c0p;
  const int bh = blockIdx.y, b = bh >> 2, h = bh & 3;
  const int n0 = blockIdx.x * 128;
  const int tid = threadIdx.x, lane = tid & 63, wid = tid >> 6;
  const int l15 = lane & 15, q = lane >> 4;
  __shared__ bf16_t sV[128 * KS];
  __shared__ bf16_t sP[C4 * KS];
  const f32x4 fz = {0.f, 0.f, 0.f, 0.f};
  f32x4 acc[2][NF];
  for (int i = 0; i < 2; i++) for (int f = 0; f < NF; f++) acc[i][f] = fz;
  const bf16_t* vrow = v + ((size_t)bh * N_ + n0) * 240;
  const float* pb = pr + (size_t)bh * C4 * 240;
  for (int k0 = 0; k0 < 256; k0 += 32) {
    __syncthreads();
    for (int idx = tid; idx < 512; idx += 256) {  // V uint4
      int r = idx >> 2, g = idx & 3, k = k0 + g * 8;
      if (k < 240) *(uint4*)&sV[r * KS + g * 8] = *(const uint4*)(vrow + (size_t)r * 240 + k);
      else *(uint4*)&sV[r * KS + g * 8] = make_uint4(0u, 0u, 0u, 0u);
    }
    for (int idx = tid; idx < C4 * 8; idx += 256) {  // P fp32 -> bf16 packed
      int cc = idx >> 3, cg = idx & 7, k = k0 + cg * 4;
      if (k < 240) stpk4(&sP[cc * KS + cg * 4], *(const float4*)(pb + (size_t)cc * 240 + k));
      else stz8(&sP[cc * KS + cg * 4]);
    }
    __syncthreads();
    const bf16_t* ap = &sV[(wid * 32 + l15) * KS + q * 8];
    bf16x8 a0 = *(const bf16x8*)ap;
    bf16x8 a1 = *(const bf16x8*)(ap + 16 * KS);
    for (int f = 0; f < NF; f++) {
      bf16x8 bb = *(const bf16x8*)&sP[(16 * f + l15) * KS + q * 8];
      acc[0][f] = mfma_bf16(a0, bb, acc[0][f]);
      acc[1][f] = mfma_bf16(a1, bb, acc[1][f]);
    }
  }
  bf16_t* crow = ctx + ((size_t)b * N_ + n0) * 960 + chof + h * C4;
  for (int i = 0; i < 2; i++)
    for (int f = 0; f < NF; f++)
      for (int r = 0; r < 4; r++) {
        int mm = wid * 32 + 16 * i + q * 4 + r;
        crow[(size_t)mm * 960 + 16 * f + l15] = (bf16_t)acc[i][f][r];
      }
}

// ============ out[b,n,obase+d] = sum_c ctx[b,n,chof+c] * Wob[d,c]   (fp32 out)
template <int CS>
__global__ __launch_bounds__(256) void k_wout(
    const bf16_t* __restrict__ c0p, const bf16_t* __restrict__ w0, int ob0,
    const bf16_t* __restrict__ c1p, const bf16_t* __restrict__ w1, int ob1,
    float* __restrict__ out, int chof) {
  constexpr int DT = (CS < 128) ? CS : 128;
  constexpr int NF = DT / 16;
  constexpr int DB = CS / DT;
  const int mod = blockIdx.z / DB, dch = blockIdx.z % DB;
  const bf16_t* ctx = mod ? c1p : c0p;
  const bf16_t* w = mod ? w1 : w0;
  const int obase = (mod ? ob1 : ob0) + dch * DT;
  const int m0 = blockIdx.x * 128;
  const int b = m0 >> 12, n0 = m0 & 4095;
  const int tid = threadIdx.x, lane = tid & 63, wid = tid >> 6;
  const int l15 = lane & 15, q = lane >> 4;
  __shared__ bf16_t sA[128 * KS];
  __shared__ bf16_t sB[DT * KS];
  const f32x4 fz = {0.f, 0.f, 0.f, 0.f};
  f32x4 acc[2][NF];
  for (int i = 0; i < 2; i++) for (int f = 0; f < NF; f++) acc[i][f] = fz;
  const bf16_t* arow = ctx + ((size_t)b * N_ + n0) * 960 + chof;
  const bf16_t* wb = w + (size_t)dch * DT * CS;
  for (int k0 = 0; k0 < CS; k0 += 32) {
    __syncthreads();
    for (int idx = tid; idx < 512; idx += 256) {  // ctx uint4
      int r = idx >> 2, g = idx & 3, k = k0 + g * 8;
      *(uint4*)&sA[r * KS + g * 8] = *(const uint4*)(arow + (size_t)r * 960 + k);
    }
    for (int idx = tid; idx < DT * 4; idx += 256) {  // W uint4 (bf16 pre-converted)
      int dd = idx >> 2, g = idx & 3, k = k0 + g * 8;
      *(uint4*)&sB[dd * KS + g * 8] = *(const uint4*)(wb + (size_t)dd * CS + k);
    }
    __syncthreads();
    const bf16_t* ap = &sA[(wid * 32 + l15) * KS + q * 8];
    bf16x8 a0 = *(const bf16x8*)ap;
    bf16x8 a1 = *(const bf16x8*)(ap + 16 * KS);
    for (int f = 0; f < NF; f++) {
      bf16x8 bb = *(const bf16x8*)&sB[(16 * f + l15) * KS + q * 8];
      acc[0][f] = mfma_bf16(a0, bb, acc[0][f]);
      acc[1][f] = mfma_bf16(a1, bb, acc[1][f]);
    }
  }
  float* orow = out + ((size_t)b * N_ + n0) * 1920 + obase;
  for (int i = 0; i < 2; i++)
    for (int f = 0; f < NF; f++)
      for (int r = 0; r < 4; r++) {
        int mm = wid * 32 + 16 * i + q * 4 + r;
        orow[(size_t)mm * 1920 + 16 * f + l15] = acc[i][f][r];
      }
}

extern "C" void kernel_launch(void* const* d_in, const int* in_sizes, int n_in,
                              void* d_out, int out_size, void* d_ws, size_t ws_size,
                              hipStream_t stream) {
  (void)in_sizes; (void)n_in; (void)out_size; (void)ws_size;
  const float* emb[2][4];
  const float* wq[2][4];
  const float* wo[2][4];
  for (int s = 0; s < 4; s++) {
    emb[0][s] = (const float*)d_in[2 * s];
    emb[1][s] = (const float*)d_in[2 * s + 1];
    wq[0][s] = (const float*)d_in[10 + 4 * s];
    wq[1][s] = (const float*)d_in[11 + 4 * s];
    wo[0][s] = (const float*)d_in[12 + 4 * s];
    wo[1][s] = (const float*)d_in[13 + 4 * s];
  }
  const float* emb_all = (const float*)d_in[8];
  const float* emb_alld = (const float*)d_in[9];
  const float* wkp = (const float*)d_in[26];
  const float* wvp = (const float*)d_in[27];
  const float* wkdp = (const float*)d_in[28];
  const float* wvdp = (const float*)d_in[29];
  float* out = (float*)d_out;

  // ws layout: [Kt0 Kt1 V0 V1 Q0/ctx0 Q1/ctx1 : bf16, 6*KV1] [probs fp32 2*PB1] [Wkvb][Wob]
  bf16_t* w16 = (bf16_t*)d_ws;
  const size_t KV1 = (size_t)B_ * H_ * N_ * 240;  // 15,728,640
  const size_t PB1 = (size_t)B_ * H_ * 240 * 240;
  bf16_t* Kt0 = w16;
  bf16_t* Kt1 = w16 + KV1;
  bf16_t* V0 = w16 + 2 * KV1;
  bf16_t* V1 = w16 + 3 * KV1;
  bf16_t* Qb = w16 + 4 * KV1;              // Q region (2*KV1); reused as ctx after scores
  float* probs = (float*)(w16 + 6 * KV1);
  bf16_t* Wkvb = (bf16_t*)(probs + 2 * PB1);
  bf16_t* Wob = Wkvb + 230400;
  const int qcum[4] = {0, 16, 48, 112};
  const int chof[4] = {0, 64, 192, 448};
  const int soff[4] = {0, 4096, 20480, 86016};
  const dim3 blk(256);

  k_prep_w<<<dim3(256), blk, 0, stream>>>(wkp, wvp, wkdp, wvdp,
      wo[0][0], wo[0][1], wo[0][2], wo[0][3], wo[1][0], wo[1][1], wo[1][2], wo[1][3],
      Wkvb, Wob);
  hipMemsetAsync(probs, 0, 2 * PB1 * sizeof(float), stream);

  // --- Q projections ---
  for (int s = 0; s < 4; s++) {
    bf16_t* q0 = Qb + (size_t)B_ * H_ * N_ * qcum[s];
    bf16_t* q1 = q0 + KV1;
    dim3 g(B_ * N_ / 128, H_, 2);
    switch (s) {
      case 0: k_proj_q<16><<<g, blk, 0, stream>>>(emb[0][s], wq[0][s], q0, emb[1][s], wq[1][s], q1); break;
      case 1: k_proj_q<32><<<g, blk, 0, stream>>>(emb[0][s], wq[0][s], q0, emb[1][s], wq[1][s], q1); break;
      case 2: k_proj_q<64><<<g, blk, 0, stream>>>(emb[0][s], wq[0][s], q0, emb[1][s], wq[1][s], q1); break;
      case 3: k_proj_q<128><<<g, blk, 0, stream>>>(emb[0][s], wq[0][s], q0, emb[1][s], wq[1][s], q1); break;
    }
  }
  // --- K/V projections (K transposed) ---
  k_proj_kv<<<dim3(B_ * H_ * N_ / 128, 4), blk, 0, stream>>>(
      emb_all, emb_alld, Wkvb, Kt0, V0, Kt1, V1);
  // --- scores: optical Q (mod0) x Kd^T (Kt1); DSM Q (mod1) x K^T (Kt0) ---
  for (int s = 0; s < 4; s++) {
    const bf16_t* q0 = Qb + (size_t)B_ * H_ * N_ * qcum[s];
    const bf16_t* q1 = q0 + KV1;
    float* p0 = probs + (size_t)B_ * H_ * qcum[s] * 240;
    float* p1 = p0 + PB1;
    const int c4 = 16 << s;
    dim3 g(c4 / 16, B_ * H_, 16);
    switch (s) {
      case 0: k_scores<16><<<g, blk, 0, stream>>>(q0, Kt1, p0, q1, Kt0, p1); break;
      case 1: k_scores<32><<<g, blk, 0, stream>>>(q0, Kt1, p0, q1, Kt0, p1); break;
      case 2: k_scores<64><<<g, blk, 0, stream>>>(q0, Kt1, p0, q1, Kt0, p1); break;
      case 3: k_scores<128><<<g, blk, 0, stream>>>(q0, Kt1, p0, q1, Kt0, p1); break;
    }
  }
  // --- InstanceNorm + softmax ---
  for (int s = 0; s < 4; s++) {
    float* p0 = probs + (size_t)B_ * H_ * qcum[s] * 240;
    float* p1 = p0 + PB1;
    k_inorm_softmax<<<dim3(B_ * H_, 1, 2), blk, 0, stream>>>(p0, p1, 16 << s);
  }
  // --- PV (optical uses Vd=V1, DSM uses V0); ctx overlays Q region ---
  for (int s = 0; s < 4; s++) {
    float* p0 = probs + (size_t)B_ * H_ * qcum[s] * 240;
    float* p1 = p0 + PB1;
    bf16_t* cx0 = Qb;
    bf16_t* cx1 = Qb + KV1;
    dim3 g(N_ / 128, B_ * H_, 2);
    switch (s) {
      case 0: k_pv<16><<<g, blk, 0, stream>>>(p0, V1, cx0, p1, V0, cx1, chof[s]); break;
      case 1: k_pv<32><<<g, blk, 0, stream>>>(p0, V1, cx0, p1, V0, cx1, chof[s]); break;
      case 2: k_pv<64><<<g, blk, 0, stream>>>(p0, V1, cx0, p1, V0, cx1, chof[s]); break;
      case 3: k_pv<128><<<g, blk, 0, stream>>>(p0, V1, cx0, p1, V0, cx1, chof[s]); break;
    }
  }
  // --- output projection (bf16 weights) ---
  for (int s = 0; s < 4; s++) {
    const bf16_t* cx0 = Qb;
    const bf16_t* cx1 = Qb + KV1;
    const bf16_t* w0 = Wob + soff[s];
    const bf16_t* w1 = Wob + 348160 + soff[s];
    const int cs = 64 << s;
    const int db = (cs < 128) ? 1 : cs / 128;
    dim3 g(B_ * N_ / 128, 1, 2 * db);
    switch (s) {
      case 0: k_wout<64><<<g, blk, 0, stream>>>(cx0, w0, chof[s], cx1, w1, 960 + chof[s], out, chof[s]); break;
      case 1: k_wout<128><<<g, blk, 0, stream>>>(cx0, w0, chof[s], cx1, w1, 960 + chof[s], out, chof[s]); break;
      case 2: k_wout<256><<<g, blk, 0, stream>>>(cx0, w0, chof[s], cx1, w1, 960 + chof[s], out, chof[s]); break;
      case 3: k_wout<512><<<g, blk, 0, stream>>>(cx0, w0, chof[s], cx1, w1, 960 + chof[s], out, chof[s]); break;
    }
  }
}